// Round 1
// baseline (273.628 us; speedup 1.0000x reference)
//
#include <hip/hip_runtime.h>
#include <hip/hip_fp16.h>

// SpikingLinearAttention forward.
// out[b,s,f] = q_s * (cumsum_s(k_s*v_f)+eps)/(cumsum_s(k_s)+eps)
// where x_f = exp(x) @ W, gated by (x_f > 0.5).
//
// Gates are discontinuous at 0.5 -> feature GEMMs must be f32 (VALU).
// Post-gate k_s / k_s*v_f are stored packed fp16 in d_out between K1 and K3
// (safe: no discontinuity left, ~5e-4 relative error vs 2%-of-absmax threshold).

constexpr int cB = 32;
constexpr int cS = 8192;
constexpr int cD = 64;
constexpr int cF = 128;
constexpr int CHUNK = 64;          // timesteps per block
constexpr int HALF = 32;           // K1 stages exp rows in half-chunks (16 KiB LDS)
constexpr int NCH = cS / CHUNK;    // 128 chunks per batch
constexpr float SPIKE_TH = 0.5f;
constexpr float EPS_ = 1e-8f;

// ---------------- K1: k/v features, gate, pack fp16, chunk partial sums ----
__global__ __launch_bounds__(cF) void k_feat(const float* __restrict__ K,
                                             const float* __restrict__ V,
                                             const float* __restrict__ W,
                                             __half2* __restrict__ packed,
                                             float* __restrict__ pk,
                                             float* __restrict__ pkv)
{
    __shared__ float ek[HALF * cD];   // exp(k rows), 8 KiB
    __shared__ float ev[HALF * cD];   // exp(v rows), 8 KiB
    const int b = blockIdx.y, c = blockIdx.x, t = threadIdx.x; // t = feature

    // W column f=t into registers. Lanes read consecutive addresses -> coalesced,
    // W is 32 KiB -> L2-resident after the first blocks.
    float wcol[cD];
#pragma unroll
    for (int d = 0; d < cD; ++d) wcol[d] = W[d * cF + t];

    const size_t rowbase = ((size_t)b * cS + (size_t)c * CHUNK) * cD;
    const float4* __restrict__ K4 = (const float4*)(K + rowbase);
    const float4* __restrict__ V4 = (const float4*)(V + rowbase);

    const size_t obase = ((size_t)b * cS + (size_t)c * CHUNK) * cF + t;
    float ksum = 0.f, kvsum = 0.f;

    for (int h = 0; h < CHUNK / HALF; ++h) {
        // cooperatively load + exp HALF rows of k and v into LDS (contiguous 8 KiB each)
        float4* ek4 = (float4*)ek;
        float4* ev4 = (float4*)ev;
        const int off = h * (HALF * cD / 4);
#pragma unroll
        for (int i = t; i < HALF * cD / 4; i += cF) {
            float4 a = K4[off + i];
            ek4[i] = make_float4(__expf(a.x), __expf(a.y), __expf(a.z), __expf(a.w));
            float4 bb = V4[off + i];
            ev4[i] = make_float4(__expf(bb.x), __expf(bb.y), __expf(bb.z), __expf(bb.w));
        }
        __syncthreads();

        for (int s = 0; s < HALF; ++s) {
            const float4* e4 = (const float4*)(ek + s * cD); // broadcast reads
            const float4* f4 = (const float4*)(ev + s * cD);
            float kf = 0.f, vf = 0.f;
#pragma unroll
            for (int d4 = 0; d4 < cD / 4; ++d4) {
                float4 a = e4[d4];
                float4 bb = f4[d4];
                kf = fmaf(a.x, wcol[4 * d4 + 0], kf);
                kf = fmaf(a.y, wcol[4 * d4 + 1], kf);
                kf = fmaf(a.z, wcol[4 * d4 + 2], kf);
                kf = fmaf(a.w, wcol[4 * d4 + 3], kf);
                vf = fmaf(bb.x, wcol[4 * d4 + 0], vf);
                vf = fmaf(bb.y, wcol[4 * d4 + 1], vf);
                vf = fmaf(bb.z, wcol[4 * d4 + 2], vf);
                vf = fmaf(bb.w, wcol[4 * d4 + 3], vf);
            }
            float ks = (kf > SPIKE_TH) ? kf : 0.f;   // gate (f32, exact)
            float kv = ks * vf;
            ksum += ks;
            kvsum += kv;
            __half2 h2;
            h2.x = __float2half_rn(ks);
            h2.y = __float2half_rn(kv);
            packed[obase + (size_t)(h * HALF + s) * cF] = h2;
        }
        __syncthreads();
    }
    const size_t pidx = ((size_t)b * NCH + c) * cF + t;
    pk[pidx] = ksum;
    pkv[pidx] = kvsum;
}

// ---------------- K2: exclusive scan of chunk partials per (b,f) ------------
__global__ __launch_bounds__(cF) void k_scan(float* __restrict__ pk,
                                             float* __restrict__ pkv)
{
    const int b = blockIdx.x, f = threadIdx.x;
    float rk = 0.f, rkv = 0.f;
    for (int c = 0; c < NCH; ++c) {
        const size_t i = ((size_t)b * NCH + c) * cF + f;
        float a = pk[i], bb = pkv[i];
        pk[i] = rk;
        pkv[i] = rkv;
        rk += a;
        rkv += bb;
    }
}

// ---------------- K3: q features + in-chunk cumsum + output (in-place) ------
__global__ __launch_bounds__(cF) void k_out(const float* __restrict__ Q,
                                            const float* __restrict__ W,
                                            float* __restrict__ out,
                                            const float* __restrict__ pk,
                                            const float* __restrict__ pkv)
{
    __shared__ float eq[CHUNK * cD];  // exp(q rows), 16 KiB
    const int b = blockIdx.y, c = blockIdx.x, t = threadIdx.x;

    float wcol[cD];
#pragma unroll
    for (int d = 0; d < cD; ++d) wcol[d] = W[d * cF + t];

    const size_t rowbase = ((size_t)b * cS + (size_t)c * CHUNK) * cD;
    const float4* __restrict__ Q4 = (const float4*)(Q + rowbase);
    float4* eq4 = (float4*)eq;
#pragma unroll
    for (int i = t; i < CHUNK * cD / 4; i += cF) {
        float4 a = Q4[i];
        eq4[i] = make_float4(__expf(a.x), __expf(a.y), __expf(a.z), __expf(a.w));
    }
    __syncthreads();

    const size_t pidx = ((size_t)b * NCH + c) * cF + t;
    float kcum = pk[pidx];   // exclusive chunk offset
    float kvcum = pkv[pidx];

    size_t idx = ((size_t)b * cS + (size_t)c * CHUNK) * cF + t;
    const __half2* __restrict__ packed = (const __half2*)out;
    for (int s = 0; s < CHUNK; ++s) {
        const float4* e4 = (const float4*)(eq + s * cD);
        float qf = 0.f;
#pragma unroll
        for (int d4 = 0; d4 < cD / 4; ++d4) {
            float4 a = e4[d4];
            qf = fmaf(a.x, wcol[4 * d4 + 0], qf);
            qf = fmaf(a.y, wcol[4 * d4 + 1], qf);
            qf = fmaf(a.z, wcol[4 * d4 + 2], qf);
            qf = fmaf(a.w, wcol[4 * d4 + 3], qf);
        }
        float qs = (qf > SPIKE_TH) ? qf : 0.f;
        __half2 h2 = packed[idx];            // read packed BEFORE overwrite (same thread)
        kcum += __half2float(h2.x);
        kvcum += __half2float(h2.y);
        float attn = (kvcum + EPS_) / (kcum + EPS_);
        out[idx] = qs * attn;
        idx += cF;
    }
}

// ---------------------------------------------------------------------------
extern "C" void kernel_launch(void* const* d_in, const int* in_sizes, int n_in,
                              void* d_out, int out_size, void* d_ws, size_t ws_size,
                              hipStream_t stream) {
    const float* q = (const float*)d_in[0];
    const float* k = (const float*)d_in[1];
    const float* v = (const float*)d_in[2];
    const float* w = (const float*)d_in[3];
    float* out = (float*)d_out;

    float* pk = (float*)d_ws;                       // (B, NCH, F) f32, 2 MiB
    float* pkv = pk + (size_t)cB * NCH * cF;        // (B, NCH, F) f32, 2 MiB

    dim3 grid(NCH, cB);
    k_feat<<<grid, cF, 0, stream>>>(k, v, w, (__half2*)d_out, pk, pkv);
    k_scan<<<cB, cF, 0, stream>>>(pk, pkv);
    k_out<<<grid, cF, 0, stream>>>(q, w, out, pk, pkv);
}

// Round 2
// 172.224 us; speedup vs baseline: 1.5888x; 1.5888x over previous
//
#include <hip/hip_runtime.h>
#include <hip/hip_fp16.h>

// SpikingLinearAttention forward, MFMA version.
// features = exp(X) @ W computed as 6-term bf16-split MFMA (full f32-dot precision):
//   x = x0+x1+x2 (bf16 pieces, residuals exact in f32); keep a0w0, a0w1, a1w0,
//   a1w1, a0w2, a2w0 (dropped terms < 2^-26 relative).
// Gates evaluated in f32 on the MFMA accumulator. Post-gate {k_s, k_s*v_f}
// packed fp16 into d_out between K1 and K3 (read-before-overwrite in K3).

constexpr int cB = 32;
constexpr int cS = 8192;
constexpr int cD = 64;
constexpr int cF = 128;
constexpr int CHUNK = 64;
constexpr int NCH = cS / CHUNK;   // 128
constexpr float EPS_ = 1e-8f;

typedef __attribute__((ext_vector_type(8))) short bf16x8;  // 8 bf16 (4 VGPRs)
typedef __attribute__((ext_vector_type(4))) float f32x4;   // 4 f32 acc

#define MFMA16(a, b, c) __builtin_amdgcn_mfma_f32_16x16x32_bf16((a), (b), (c), 0, 0, 0)

// ---- bf16 round-to-nearest-even helpers -----------------------------------
__device__ __forceinline__ unsigned short bf16rn(float x) {
    unsigned u = __float_as_uint(x);
    unsigned r = u + 0x7FFFu + ((u >> 16) & 1u);
    return (unsigned short)(r >> 16);
}
__device__ __forceinline__ float bf16tof(unsigned short h) {
    return __uint_as_float((unsigned)h << 16);
}
__device__ __forceinline__ void split3(float x, unsigned short& a0,
                                       unsigned short& a1, unsigned short& a2) {
    a0 = bf16rn(x);
    float r1 = x - bf16tof(a0);   // exact
    a1 = bf16rn(r1);
    float r2 = r1 - bf16tof(a1);  // exact
    a2 = bf16rn(r2);
}

// A-fragment layout (16x16x32 bf16): lane l holds A[l&15][(l>>4)*8 + j], j=0..7.
// B-fragment: lane l holds B[(l>>4)*8 + j][l&15].
// C/D: lane l, reg r -> row (l>>4)*4+r, col l&15.   [m89-verified]

// ---- K0: split W (64x128) into 3 bf16 matrices in B-frag order ------------
// slot = (ntile*2 + kstep)*3 + split ; ushort index = slot*512 + lane*8 + j
__global__ __launch_bounds__(256) void k_wsplit(const float* __restrict__ W,
                                                unsigned short* __restrict__ ws) {
    for (int i = threadIdx.x; i < cD * cF; i += 256) {
        int d = i >> 7, f = i & 127;
        unsigned short s0, s1, s2;
        split3(W[i], s0, s1, s2);
        int n = f >> 4, k = d >> 5;
        int lane = (f & 15) | (((d >> 3) & 3) << 4);
        int j = d & 7;
        int base = ((n * 2 + k) * 3) * 512 + lane * 8 + j;
        ws[base]        = s0;
        ws[base + 512]  = s1;
        ws[base + 1024] = s2;
    }
}

// ---- K1: k/v features via MFMA, gate, pack fp16, chunk partial sums -------
__global__ __launch_bounds__(256, 2) void k_feat(const float* __restrict__ K,
                                                 const float* __restrict__ V,
                                                 const unsigned short* __restrict__ wsplit,
                                                 __half2* __restrict__ packed,
                                                 float* __restrict__ pk,
                                                 float* __restrict__ pkv)
{
    // A-frags for exp(K) and exp(V): 24 slots (4 mtiles x 2 ksteps x 3 splits) x 512 ushorts
    __shared__ unsigned short afK[24 * 512];
    __shared__ unsigned short afV[24 * 512];
    const int b = blockIdx.y, c = blockIdx.x;
    const int t = threadIdx.x, w = t >> 6, l = t & 63;

    // B-frags for this wave's two n-tiles (issue early; L2-hot)
    bf16x8 wf[2][2][3];
#pragma unroll
    for (int n = 0; n < 2; ++n)
#pragma unroll
        for (int k = 0; k < 2; ++k)
#pragma unroll
            for (int p = 0; p < 3; ++p) {
                int slot = ((2 * w + n) * 2 + k) * 3 + p;
                wf[n][k][p] = *(const bf16x8*)(wsplit + slot * 512 + l * 8);
            }

    // stage exp(K), exp(V) splits into frag-ordered LDS
    const size_t rowbase = ((size_t)b * cS + (size_t)c * CHUNK) * cD;
#pragma unroll
    for (int mat = 0; mat < 2; ++mat) {
        const float4* src = (const float4*)((mat ? V : K) + rowbase);
        unsigned short* af = mat ? afV : afK;
#pragma unroll
        for (int i = 0; i < 4; ++i) {
            int idx = t + i * 256;            // float4 index in 64x64
            int row = idx >> 4, c4 = (idx & 15) * 4;
            float4 a = src[idx];
            float e[4] = {__expf(a.x), __expf(a.y), __expf(a.z), __expf(a.w)};
            unsigned short s[3][4];
#pragma unroll
            for (int q = 0; q < 4; ++q) split3(e[q], s[0][q], s[1][q], s[2][q]);
            int m = row >> 4, k = c4 >> 5;
            int lane = (row & 15) | (((c4 >> 3) & 3) << 4);
            int j = c4 & 7;                   // 0 or 4
            int base = (m * 2 + k) * 3 * 512 + lane * 8 + j;
#pragma unroll
            for (int p = 0; p < 3; ++p) {
                uint2 v;
                v.x = (unsigned)s[p][0] | ((unsigned)s[p][1] << 16);
                v.y = (unsigned)s[p][2] | ((unsigned)s[p][3] << 16);
                *(uint2*)&af[base + p * 512] = v;
            }
        }
    }
    __syncthreads();

    f32x4 accK[4][2] = {};
    f32x4 accV[4][2] = {};
#pragma unroll
    for (int m = 0; m < 4; ++m)
#pragma unroll
        for (int k = 0; k < 2; ++k) {
            int bs = (m * 2 + k) * 3 * 512 + l * 8;
            bf16x8 aK[3], aV[3];
#pragma unroll
            for (int p = 0; p < 3; ++p) {
                aK[p] = *(const bf16x8*)&afK[bs + p * 512];
                aV[p] = *(const bf16x8*)&afV[bs + p * 512];
            }
#pragma unroll
            for (int n = 0; n < 2; ++n) {
                accK[m][n] = MFMA16(aK[0], wf[n][k][0], accK[m][n]);
                accK[m][n] = MFMA16(aK[0], wf[n][k][1], accK[m][n]);
                accK[m][n] = MFMA16(aK[1], wf[n][k][0], accK[m][n]);
                accK[m][n] = MFMA16(aK[1], wf[n][k][1], accK[m][n]);
                accK[m][n] = MFMA16(aK[0], wf[n][k][2], accK[m][n]);
                accK[m][n] = MFMA16(aK[2], wf[n][k][0], accK[m][n]);
                accV[m][n] = MFMA16(aV[0], wf[n][k][0], accV[m][n]);
                accV[m][n] = MFMA16(aV[0], wf[n][k][1], accV[m][n]);
                accV[m][n] = MFMA16(aV[1], wf[n][k][0], accV[m][n]);
                accV[m][n] = MFMA16(aV[1], wf[n][k][1], accV[m][n]);
                accV[m][n] = MFMA16(aV[0], wf[n][k][2], accV[m][n]);
                accV[m][n] = MFMA16(aV[2], wf[n][k][0], accV[m][n]);
            }
        }

    // epilogue: gate, pack, store, and per-feature chunk sums
    const size_t obase = ((size_t)b * cS + (size_t)c * CHUNK) * cF;
    float ksum[2] = {0.f, 0.f}, kvsum[2] = {0.f, 0.f};
#pragma unroll
    for (int m = 0; m < 4; ++m)
#pragma unroll
        for (int n = 0; n < 2; ++n) {
            int f = w * 32 + n * 16 + (l & 15);
#pragma unroll
            for (int r = 0; r < 4; ++r) {
                int s = m * 16 + (l >> 4) * 4 + r;
                float kf = accK[m][n][r], vf = accV[m][n][r];
                float ks = (kf > 0.5f) ? kf : 0.f;
                float kv = ks * vf;
                ksum[n] += ks;
                kvsum[n] += kv;
                __half2 h2;
                h2.x = __float2half_rn(ks);
                h2.y = __float2half_rn(kv);
                packed[obase + (size_t)s * cF + f] = h2;
            }
        }
#pragma unroll
    for (int n = 0; n < 2; ++n) {
        float a = ksum[n], bb = kvsum[n];
        a += __shfl_xor(a, 16);  a += __shfl_xor(a, 32);
        bb += __shfl_xor(bb, 16); bb += __shfl_xor(bb, 32);
        if ((l >> 4) == 0) {
            size_t pi = ((size_t)b * NCH + c) * cF + w * 32 + n * 16 + l;
            pk[pi] = a;
            pkv[pi] = bb;
        }
    }
}

// ---- K2: exclusive scan of chunk partials per (b,f) -----------------------
__global__ __launch_bounds__(cF) void k_scan(float* __restrict__ pk,
                                             float* __restrict__ pkv)
{
    const int b = blockIdx.x, f = threadIdx.x;
    float rk = 0.f, rkv = 0.f;
    for (int c = 0; c < NCH; ++c) {
        const size_t i = ((size_t)b * NCH + c) * cF + f;
        float a = pk[i], bb = pkv[i];
        pk[i] = rk;
        pkv[i] = rkv;
        rk += a;
        rkv += bb;
    }
}

// ---- K3: q features via MFMA + in-chunk cumsum + output (in-place) --------
__global__ __launch_bounds__(256, 2) void k_out(const float* __restrict__ Q,
                                                const unsigned short* __restrict__ wsplit,
                                                float* __restrict__ out,
                                                const float* __restrict__ pk,
                                                const float* __restrict__ pkv)
{
    __shared__ float qs_l[CHUNK * 132];             // 33 KiB, stride 132 (bank-safe)
    unsigned short* afQ = (unsigned short*)qs_l;    // aliased A-frag region (24 KiB)
    const int b = blockIdx.y, c = blockIdx.x;
    const int t = threadIdx.x, w = t >> 6, l = t & 63;

    bf16x8 wf[2][2][3];
#pragma unroll
    for (int n = 0; n < 2; ++n)
#pragma unroll
        for (int k = 0; k < 2; ++k)
#pragma unroll
            for (int p = 0; p < 3; ++p) {
                int slot = ((2 * w + n) * 2 + k) * 3 + p;
                wf[n][k][p] = *(const bf16x8*)(wsplit + slot * 512 + l * 8);
            }

    const size_t rowbase = ((size_t)b * cS + (size_t)c * CHUNK) * cD;
    {
        const float4* src = (const float4*)(Q + rowbase);
#pragma unroll
        for (int i = 0; i < 4; ++i) {
            int idx = t + i * 256;
            int row = idx >> 4, c4 = (idx & 15) * 4;
            float4 a = src[idx];
            float e[4] = {__expf(a.x), __expf(a.y), __expf(a.z), __expf(a.w)};
            unsigned short s[3][4];
#pragma unroll
            for (int q = 0; q < 4; ++q) split3(e[q], s[0][q], s[1][q], s[2][q]);
            int m = row >> 4, k = c4 >> 5;
            int lane = (row & 15) | (((c4 >> 3) & 3) << 4);
            int j = c4 & 7;
            int base = (m * 2 + k) * 3 * 512 + lane * 8 + j;
#pragma unroll
            for (int p = 0; p < 3; ++p) {
                uint2 v;
                v.x = (unsigned)s[p][0] | ((unsigned)s[p][1] << 16);
                v.y = (unsigned)s[p][2] | ((unsigned)s[p][3] << 16);
                *(uint2*)&afQ[base + p * 512] = v;
            }
        }
    }
    __syncthreads();

    f32x4 acc[4][2] = {};
#pragma unroll
    for (int m = 0; m < 4; ++m)
#pragma unroll
        for (int k = 0; k < 2; ++k) {
            int bs = (m * 2 + k) * 3 * 512 + l * 8;
            bf16x8 aQ[3];
#pragma unroll
            for (int p = 0; p < 3; ++p) aQ[p] = *(const bf16x8*)&afQ[bs + p * 512];
#pragma unroll
            for (int n = 0; n < 2; ++n) {
                acc[m][n] = MFMA16(aQ[0], wf[n][k][0], acc[m][n]);
                acc[m][n] = MFMA16(aQ[0], wf[n][k][1], acc[m][n]);
                acc[m][n] = MFMA16(aQ[1], wf[n][k][0], acc[m][n]);
                acc[m][n] = MFMA16(aQ[1], wf[n][k][1], acc[m][n]);
                acc[m][n] = MFMA16(aQ[0], wf[n][k][2], acc[m][n]);
                acc[m][n] = MFMA16(aQ[2], wf[n][k][0], acc[m][n]);
            }
        }
    __syncthreads();   // done reading afQ; safe to overwrite with qs

#pragma unroll
    for (int m = 0; m < 4; ++m)
#pragma unroll
        for (int n = 0; n < 2; ++n) {
            int f = w * 32 + n * 16 + (l & 15);
#pragma unroll
            for (int r = 0; r < 4; ++r) {
                int s = m * 16 + (l >> 4) * 4 + r;
                float qf = acc[m][n][r];
                qs_l[s * 132 + f] = (qf > 0.5f) ? qf : 0.f;
            }
        }
    __syncthreads();

    if (t < cF) {
        const int f = t;
        const size_t pi = ((size_t)b * NCH + c) * cF + f;
        float kcum = pk[pi], kvcum = pkv[pi];
        const size_t obase = ((size_t)b * cS + (size_t)c * CHUNK) * cF;
        size_t idx = obase + f;
        const __half2* packed = (const __half2*)out;  // aliases out; read-before-write
#pragma unroll 4
        for (int s = 0; s < CHUNK; ++s) {
            __half2 h2 = packed[idx];
            kcum += __half2float(h2.x);
            kvcum += __half2float(h2.y);
            float attn = __fdividef(kvcum + EPS_, kcum + EPS_);
            out[idx] = qs_l[s * 132 + f] * attn;
            idx += cF;
        }
    }
}

// ---------------------------------------------------------------------------
extern "C" void kernel_launch(void* const* d_in, const int* in_sizes, int n_in,
                              void* d_out, int out_size, void* d_ws, size_t ws_size,
                              hipStream_t stream) {
    const float* q = (const float*)d_in[0];
    const float* k = (const float*)d_in[1];
    const float* v = (const float*)d_in[2];
    const float* w = (const float*)d_in[3];
    float* out = (float*)d_out;

    unsigned short* wsplit = (unsigned short*)d_ws;               // 48 KiB
    float* pk = (float*)((char*)d_ws + 65536);                    // 2 MiB
    float* pkv = pk + (size_t)cB * NCH * cF;                      // 2 MiB

    k_wsplit<<<1, 256, 0, stream>>>(w, wsplit);
    dim3 grid(NCH, cB);
    k_feat<<<grid, 256, 0, stream>>>(k, v, wsplit, (__half2*)d_out, pk, pkv);
    k_scan<<<cB, cF, 0, stream>>>(pk, pkv);
    k_out<<<grid, 256, 0, stream>>>(q, wsplit, out, pk, pkv);
}